// Round 4
// baseline (438.562 us; speedup 1.0000x reference)
//
#include <hip/hip_runtime.h>
#include <stdint.h>

#define NT 256
#define ROW 8192

// Order-preserving float->uint transform (ascending uint == ascending float).
__device__ __forceinline__ uint32_t f2u(uint32_t b) {
    return (b & 0x80000000u) ? ~b : (b | 0x80000000u);
}
__device__ __forceinline__ uint32_t u2fbits(uint32_t u) {
    return (u & 0x80000000u) ? (u ^ 0x80000000u) : ~u;
}

// Given s_hist bin counts (higher bin index = larger value), find digit d such
// that cnt(digit > d) < k <= cnt(digit >= d).
// Writes s_sel[0] = d, s_sel[1] = k - cnt(digit > d). Ends with __syncthreads().
template <int B>
__device__ __forceinline__ void select_digit(const uint32_t* s_hist, uint32_t* s_wsum,
                                             uint32_t* s_sel, int t, uint32_t k) {
    // Per-thread group sum (group t owns bins [t*B, t*B+B)).
    uint32_t local = 0;
    if (B == 16) {
#pragma unroll
        for (int j = 0; j < 4; ++j) {
            uint4 h = ((const uint4*)s_hist)[t * 4 + j];
            local += h.x + h.y + h.z + h.w;
        }
    } else {  // B == 4
        uint4 h = ((const uint4*)s_hist)[t];
        local = h.x + h.y + h.z + h.w;
    }
    const int lane = t & 63;
    const int wave = t >> 6;
    // Inclusive suffix sum within the wave.
    uint32_t incl = local;
#pragma unroll
    for (int off = 1; off < 64; off <<= 1) {
        uint32_t vv = __shfl_down(incl, off, 64);
        if (lane + off < 64) incl += vv;
    }
    if (lane == 0) s_wsum[wave] = incl;  // wave total
    __syncthreads();
    uint32_t later = 0;
#pragma unroll
    for (int w = 0; w < 4; ++w)
        if (w > wave) later += s_wsum[w];
    const uint32_t sfx_incl = incl + later;       // sum over groups >= t
    const uint32_t sfx_excl = sfx_incl - local;   // sum over groups >  t
    if (sfx_excl < k && k <= sfx_incl) {
        uint32_t cum = sfx_excl;
#pragma unroll
        for (int i = B - 1; i >= 0; --i) {
            uint32_t c = s_hist[t * B + i];
            if (k <= cum + c) {
                s_sel[0] = (uint32_t)(t * B + i);
                s_sel[1] = k - cum;
                break;
            }
            cum += c;
        }
    }
    __syncthreads();
}

// Block-wide sum of a per-thread value. Ends with __syncthreads().
__device__ __forceinline__ uint32_t block_sum(uint32_t cnt, uint32_t* s_wsum, int t) {
    const int lane = t & 63;
    const int wave = t >> 6;
#pragma unroll
    for (int off = 32; off >= 1; off >>= 1) cnt += __shfl_down(cnt, off, 64);
    if (lane == 0) s_wsum[wave] = cnt;
    __syncthreads();
    uint32_t tot = s_wsum[0] + s_wsum[1] + s_wsum[2] + s_wsum[3];
    __syncthreads();  // s_wsum is reused by the next select_digit
    return tot;
}

__global__ __launch_bounds__(NT) void ksparse_rowtopk(const float* __restrict__ x,
                                                      const int* __restrict__ kp,
                                                      float* __restrict__ out) {
    __shared__ uint32_t s_hist[4096];  // 16 KiB
    __shared__ uint32_t s_wsum[4];
    __shared__ uint32_t s_sel[2];

    const int t = threadIdx.x;
    const long long rowbase = (long long)blockIdx.x * (long long)ROW;
    const uint4* xin = (const uint4*)(x + rowbase);

    // ---- load row: 8 x uint4 per thread, kept in registers for the whole kernel
    uint4 v[8];
#pragma unroll
    for (int j = 0; j < 8; ++j) v[j] = xin[j * NT + t];
#pragma unroll
    for (int j = 0; j < 8; ++j) {
        v[j].x = f2u(v[j].x);
        v[j].y = f2u(v[j].y);
        v[j].z = f2u(v[j].z);
        v[j].w = f2u(v[j].w);
    }

    int kin = *kp;
    if (kin < 1) kin = 1;
    if (kin > ROW) kin = ROW;
    uint32_t k = (uint32_t)kin;

    // ==== sample phase: 1024 strided samples -> conservative 12-bit bin bound
    // Goal: find selBin such that count(top12 >= selBin) is ~3k but >= k w.h.p.
    // Exactness is preserved: if the exact count comes back < k we fall back to
    // selBin = 0 (the original, fully-validated full-histogram path).
#pragma unroll
    for (int j = 0; j < 4; ++j)
        ((uint4*)s_hist)[j * NT + t] = make_uint4(0u, 0u, 0u, 0u);
    __syncthreads();
    atomicAdd(&s_hist[v[0].x >> 20], 1u);
    atomicAdd(&s_hist[v[2].x >> 20], 1u);
    atomicAdd(&s_hist[v[4].x >> 20], 1u);
    atomicAdd(&s_hist[v[6].x >> 20], 1u);
    __syncthreads();
    uint32_t starget = (3u * k + 7u) / 8u;  // = 3k * (1024/8192)
    if (starget < 1u) starget = 1u;
    if (starget > 1023u) starget = 1023u;
    select_digit<16>(s_hist, s_wsum, s_sel, t, starget);
    uint32_t selBin = s_sel[0];
    __syncthreads();

    // exact count of elements with top12 >= selBin (pure register compares)
    uint32_t cnt = 0;
#pragma unroll
    for (int j = 0; j < 8; ++j) {
        cnt += (v[j].x >> 20) >= selBin;
        cnt += (v[j].y >> 20) >= selBin;
        cnt += (v[j].z >> 20) >= selBin;
        cnt += (v[j].w >> 20) >= selBin;
    }
    uint32_t C = block_sum(cnt, s_wsum, t);
    if (C < k) selBin = 0u;  // fallback: full histogram (exact in all cases)

    // ---- pass 1: top 12 bits, 4096 bins, only elements with top12 >= selBin
#pragma unroll
    for (int j = 0; j < 4; ++j)
        ((uint4*)s_hist)[j * NT + t] = make_uint4(0u, 0u, 0u, 0u);
    __syncthreads();
#pragma unroll
    for (int j = 0; j < 8; ++j) {
        uint32_t bx = v[j].x >> 20, by = v[j].y >> 20, bz = v[j].z >> 20, bw = v[j].w >> 20;
        if (bx >= selBin) atomicAdd(&s_hist[bx], 1u);
        if (by >= selBin) atomicAdd(&s_hist[by], 1u);
        if (bz >= selBin) atomicAdd(&s_hist[bz], 1u);
        if (bw >= selBin) atomicAdd(&s_hist[bw], 1u);
    }
    __syncthreads();
    select_digit<16>(s_hist, s_wsum, s_sel, t, k);
    uint32_t d1 = s_sel[0];
    k = s_sel[1];
    __syncthreads();

    // ---- pass 2: bits [19:10], 1024 bins, only elements with top12 == d1
    ((uint4*)s_hist)[t] = make_uint4(0u, 0u, 0u, 0u);
    __syncthreads();
#pragma unroll
    for (int j = 0; j < 8; ++j) {
        if ((v[j].x >> 20) == d1) atomicAdd(&s_hist[(v[j].x >> 10) & 1023u], 1u);
        if ((v[j].y >> 20) == d1) atomicAdd(&s_hist[(v[j].y >> 10) & 1023u], 1u);
        if ((v[j].z >> 20) == d1) atomicAdd(&s_hist[(v[j].z >> 10) & 1023u], 1u);
        if ((v[j].w >> 20) == d1) atomicAdd(&s_hist[(v[j].w >> 10) & 1023u], 1u);
    }
    __syncthreads();
    select_digit<4>(s_hist, s_wsum, s_sel, t, k);
    uint32_t d2 = s_sel[0];
    k = s_sel[1];
    __syncthreads();

    // ---- pass 3: bits [9:0], 1024 bins, only elements with top22 == (d1<<10)|d2
    const uint32_t pfx2 = (d1 << 10) | d2;
    ((uint4*)s_hist)[t] = make_uint4(0u, 0u, 0u, 0u);
    __syncthreads();
#pragma unroll
    for (int j = 0; j < 8; ++j) {
        if ((v[j].x >> 10) == pfx2) atomicAdd(&s_hist[v[j].x & 1023u], 1u);
        if ((v[j].y >> 10) == pfx2) atomicAdd(&s_hist[v[j].y & 1023u], 1u);
        if ((v[j].z >> 10) == pfx2) atomicAdd(&s_hist[v[j].z & 1023u], 1u);
        if ((v[j].w >> 10) == pfx2) atomicAdd(&s_hist[v[j].w & 1023u], 1u);
    }
    __syncthreads();
    select_digit<4>(s_hist, s_wsum, s_sel, t, k);
    uint32_t d3 = s_sel[0];

    const uint32_t thr = (d1 << 20) | (d2 << 10) | d3;  // exact uint of kth value

    // ---- output: keep if u >= thr (== float compare via monotone transform)
    float4* orow = (float4*)(out + rowbase);
#pragma unroll
    for (int j = 0; j < 8; ++j) {
        float4 o;
        o.x = (v[j].x >= thr) ? __uint_as_float(u2fbits(v[j].x)) : 0.0f;
        o.y = (v[j].y >= thr) ? __uint_as_float(u2fbits(v[j].y)) : 0.0f;
        o.z = (v[j].z >= thr) ? __uint_as_float(u2fbits(v[j].z)) : 0.0f;
        o.w = (v[j].w >= thr) ? __uint_as_float(u2fbits(v[j].w)) : 0.0f;
        orow[j * NT + t] = o;
    }
}

extern "C" void kernel_launch(void* const* d_in, const int* in_sizes, int n_in,
                              void* d_out, int out_size, void* d_ws, size_t ws_size,
                              hipStream_t stream) {
    const float* x = (const float*)d_in[0];
    const int* kp = (const int*)d_in[1];
    float* out = (float*)d_out;
    const int rows = in_sizes[0] / ROW;  // 8192
    ksparse_rowtopk<<<dim3(rows), dim3(NT), 0, stream>>>(x, kp, out);
}

// Round 5
// 435.163 us; speedup vs baseline: 1.0078x; 1.0078x over previous
//
#include <hip/hip_runtime.h>
#include <stdint.h>

#define NT 512
#define ROW 8192
#define VPT 4  // uint4 per thread = ROW / 4 / NT

// Order-preserving float->uint transform (ascending uint == ascending float).
__device__ __forceinline__ uint32_t f2u(uint32_t b) {
    return (b & 0x80000000u) ? ~b : (b | 0x80000000u);
}
__device__ __forceinline__ uint32_t u2fbits(uint32_t u) {
    return (u & 0x80000000u) ? (u ^ 0x80000000u) : ~u;
}

// Given s_hist bin counts (higher bin index = larger value), find digit d such
// that cnt(digit > d) < k <= cnt(digit >= d).
// Writes s_sel[0] = d, s_sel[1] = k - cnt(digit > d). Ends with __syncthreads().
template <int B>
__device__ __forceinline__ void select_digit(const uint32_t* s_hist, uint32_t* s_wsum,
                                             uint32_t* s_sel, int t, uint32_t k) {
    // Per-thread group sum (group t owns bins [t*B, t*B+B)).
    uint32_t local = 0;
    if (B == 8) {
        uint4 h0 = ((const uint4*)s_hist)[t * 2];
        uint4 h1 = ((const uint4*)s_hist)[t * 2 + 1];
        local = h0.x + h0.y + h0.z + h0.w + h1.x + h1.y + h1.z + h1.w;
    } else {  // B == 2
        uint2 h = ((const uint2*)s_hist)[t];
        local = h.x + h.y;
    }
    const int lane = t & 63;
    const int wave = t >> 6;
    // Inclusive suffix sum within the wave.
    uint32_t incl = local;
#pragma unroll
    for (int off = 1; off < 64; off <<= 1) {
        uint32_t vv = __shfl_down(incl, off, 64);
        if (lane + off < 64) incl += vv;
    }
    if (lane == 0) s_wsum[wave] = incl;  // wave total
    __syncthreads();
    uint32_t later = 0;
#pragma unroll
    for (int w = 0; w < 8; ++w)
        if (w > wave) later += s_wsum[w];
    const uint32_t sfx_incl = incl + later;       // sum over groups >= t
    const uint32_t sfx_excl = sfx_incl - local;   // sum over groups >  t
    if (sfx_excl < k && k <= sfx_incl) {
        // Exactly one thread lands here; walk its B bins from the top down.
        uint32_t cum = sfx_excl;
#pragma unroll
        for (int i = B - 1; i >= 0; --i) {
            uint32_t c = s_hist[t * B + i];
            if (k <= cum + c) {
                s_sel[0] = (uint32_t)(t * B + i);
                s_sel[1] = k - cum;
                break;
            }
            cum += c;
        }
    }
    __syncthreads();
}

__global__ __launch_bounds__(NT, 8) void ksparse_rowtopk(const float* __restrict__ x,
                                                         const int* __restrict__ kp,
                                                         float* __restrict__ out) {
    __shared__ uint32_t s_hist1[4096];  // pass1 (4096 bins); low 1024 reused by pass3
    __shared__ uint32_t s_hist2[1024];  // pass2
    __shared__ uint32_t s_wsum[8];
    __shared__ uint32_t s_sel[2];

    const int t = threadIdx.x;
    const long long rowbase = (long long)blockIdx.x * (long long)ROW;
    const uint4* xin = (const uint4*)(x + rowbase);

    // ---- issue row loads: 4 x uint4 per thread, kept in registers throughout
    uint4 v[VPT];
#pragma unroll
    for (int j = 0; j < VPT; ++j) v[j] = xin[j * NT + t];

    // clear both histograms while loads are in flight
    ((uint4*)s_hist1)[t] = make_uint4(0u, 0u, 0u, 0u);
    ((uint4*)s_hist1)[t + NT] = make_uint4(0u, 0u, 0u, 0u);
    if (t < 256) ((uint4*)s_hist2)[t] = make_uint4(0u, 0u, 0u, 0u);

    int kin = *kp;
    if (kin < 1) kin = 1;
    if (kin > ROW) kin = ROW;
    uint32_t k = (uint32_t)kin;
    __syncthreads();

    // ---- pass 1: top 12 bits, 4096 bins (per-j so work starts as loads land)
#pragma unroll
    for (int j = 0; j < VPT; ++j) {
        v[j].x = f2u(v[j].x);
        v[j].y = f2u(v[j].y);
        v[j].z = f2u(v[j].z);
        v[j].w = f2u(v[j].w);
        atomicAdd(&s_hist1[v[j].x >> 20], 1u);
        atomicAdd(&s_hist1[v[j].y >> 20], 1u);
        atomicAdd(&s_hist1[v[j].z >> 20], 1u);
        atomicAdd(&s_hist1[v[j].w >> 20], 1u);
    }
    __syncthreads();
    select_digit<8>(s_hist1, s_wsum, s_sel, t, k);
    const uint32_t d1 = s_sel[0];
    k = s_sel[1];

    // ---- pass 2: bits [19:10] into s_hist2; clear s_hist1 low 1024 for pass 3
    if (t < 256) ((uint4*)s_hist1)[t] = make_uint4(0u, 0u, 0u, 0u);
#pragma unroll
    for (int j = 0; j < VPT; ++j) {
        if ((v[j].x >> 20) == d1) atomicAdd(&s_hist2[(v[j].x >> 10) & 1023u], 1u);
        if ((v[j].y >> 20) == d1) atomicAdd(&s_hist2[(v[j].y >> 10) & 1023u], 1u);
        if ((v[j].z >> 20) == d1) atomicAdd(&s_hist2[(v[j].z >> 10) & 1023u], 1u);
        if ((v[j].w >> 20) == d1) atomicAdd(&s_hist2[(v[j].w >> 10) & 1023u], 1u);
    }
    __syncthreads();
    select_digit<2>(s_hist2, s_wsum, s_sel, t, k);
    const uint32_t d2 = s_sel[0];
    k = s_sel[1];

    // ---- pass 3: bits [9:0] into s_hist1[0:1024]
    const uint32_t pfx2 = (d1 << 10) | d2;
#pragma unroll
    for (int j = 0; j < VPT; ++j) {
        if ((v[j].x >> 10) == pfx2) atomicAdd(&s_hist1[v[j].x & 1023u], 1u);
        if ((v[j].y >> 10) == pfx2) atomicAdd(&s_hist1[v[j].y & 1023u], 1u);
        if ((v[j].z >> 10) == pfx2) atomicAdd(&s_hist1[v[j].z & 1023u], 1u);
        if ((v[j].w >> 10) == pfx2) atomicAdd(&s_hist1[v[j].w & 1023u], 1u);
    }
    __syncthreads();
    select_digit<2>(s_hist1, s_wsum, s_sel, t, k);
    const uint32_t d3 = s_sel[0];

    const uint32_t thr = (d1 << 20) | (d2 << 10) | d3;  // exact uint of kth value

    // ---- output: keep if u >= thr (== float compare via monotone transform)
    float4* orow = (float4*)(out + rowbase);
#pragma unroll
    for (int j = 0; j < VPT; ++j) {
        float4 o;
        o.x = (v[j].x >= thr) ? __uint_as_float(u2fbits(v[j].x)) : 0.0f;
        o.y = (v[j].y >= thr) ? __uint_as_float(u2fbits(v[j].y)) : 0.0f;
        o.z = (v[j].z >= thr) ? __uint_as_float(u2fbits(v[j].z)) : 0.0f;
        o.w = (v[j].w >= thr) ? __uint_as_float(u2fbits(v[j].w)) : 0.0f;
        orow[j * NT + t] = o;
    }
}

extern "C" void kernel_launch(void* const* d_in, const int* in_sizes, int n_in,
                              void* d_out, int out_size, void* d_ws, size_t ws_size,
                              hipStream_t stream) {
    const float* x = (const float*)d_in[0];
    const int* kp = (const int*)d_in[1];
    float* out = (float*)d_out;
    const int rows = in_sizes[0] / ROW;  // 8192
    ksparse_rowtopk<<<dim3(rows), dim3(NT), 0, stream>>>(x, kp, out);
}